// Round 17
// baseline (497.590 us; speedup 1.0000x reference)
//
#include <hip/hip_runtime.h>
#include <math.h>

#define NN 50000
#define NE 800000
#define FDIM 128
#define CLS 40
#define AW 512    // hidden A width: 4 Chebyshev slices of 128
#define ZW 256    // last-layer Z width: 4 slices of 64 (40 used)

// CSR-by-bucket-sort parameters
#define BSH 7
#define BINS 128
#define NBUK 391
#define NB_E 196
#define EUNITS 1024
#define U4 (NE / 4)
#define HL (NBUK * NB_E)
#define HL2 (2 * HL)
#define SCAN_CHUNK 2048
#define NB_S ((HL2 + SCAN_CHUNK - 1) / SCAN_CHUNK)
#define BSLACK 4096

typedef __attribute__((ext_vector_type(8))) short short8v;
typedef __attribute__((ext_vector_type(8))) unsigned short ushort8v;
typedef __attribute__((ext_vector_type(4))) float f32x4;

__device__ inline float b2f(unsigned short u) {
    union { unsigned int i; float f; } v; v.i = ((unsigned)u) << 16; return v.f;
}
__device__ inline unsigned short f2b(float f) {
    unsigned int x = __float_as_uint(f);
    unsigned int r = (x + 0x7fffu + ((x >> 16) & 1u)) >> 16;
    return (unsigned short)r;
}
// sext byte j of word w -> float
__device__ inline float sb(int w, int j) {
    return (float)((w << (24 - 8 * j)) >> 24);
}
// pack 8 quantized floats -> int2
__device__ inline int2 qpack(const float* f, float scale) {
    int2 r; r.x = 0; r.y = 0;
    #pragma unroll
    for (int j = 0; j < 4; j++) r.x |= (((int)rintf(f[j] * scale)) & 0xff) << (8 * j);
    #pragma unroll
    for (int j = 0; j < 4; j++) r.y |= (((int)rintf(f[4 + j] * scale)) & 0xff) << (8 * j);
    return r;
}

// ---------------- fused prep: [dual-hist | cvtx+quant | wprep0 | wprep1 | wprep_z] ----------------
#define NB_CVT  3125
#define NB_WH   256
#define NB_WZ   128

__global__ __launch_bounds__(256) void prep_k(
        const int4* __restrict__ esrc4, const int4* __restrict__ edst4,
        int* __restrict__ hist,
        const float* __restrict__ x, unsigned short* __restrict__ Ab,
        signed char* __restrict__ Q0, float* __restrict__ rm0,
        const float* __restrict__ W0, const float* __restrict__ W1,
        const float* __restrict__ W2,
        unsigned short* __restrict__ Wt0, unsigned short* __restrict__ Wt1,
        unsigned short* __restrict__ Wz) {
    int b = blockIdx.x;
    int tid = threadIdx.x;
    if (b < NB_E) {
        __shared__ int lcd[NBUK], lcs[NBUK];
        for (int i = tid; i < NBUK; i += 256) { lcd[i] = 0; lcs[i] = 0; }
        __syncthreads();
        #pragma unroll
        for (int it = 0; it < 4; it++) {
            int u = b * EUNITS + it * 256 + tid;
            if (u < U4) {
                int4 s = esrc4[u], d = edst4[u];
                atomicAdd(&lcd[d.x >> BSH], 1); atomicAdd(&lcd[d.y >> BSH], 1);
                atomicAdd(&lcd[d.z >> BSH], 1); atomicAdd(&lcd[d.w >> BSH], 1);
                atomicAdd(&lcs[s.x >> BSH], 1); atomicAdd(&lcs[s.y >> BSH], 1);
                atomicAdd(&lcs[s.z >> BSH], 1); atomicAdd(&lcs[s.w >> BSH], 1);
            }
        }
        __syncthreads();
        for (int i = tid; i < NBUK; i += 256) {
            hist[i * NB_E + b] = lcd[i];
            hist[HL + i * NB_E + b] = lcs[i];
        }
    } else if (b < NB_E + NB_CVT) {
        int i = (b - NB_E) * 256 + tid;   // < NN*16
        int row = i >> 4, cg = i & 15;
        const float4* xp = (const float4*)(x + (size_t)row * FDIM + cg * 8);
        float4 v0 = xp[0], v1 = xp[1];
        float f[8] = {v0.x, v0.y, v0.z, v0.w, v1.x, v1.y, v1.z, v1.w};
        ushort8v r;
        float m = 0.0f;
        #pragma unroll
        for (int j = 0; j < 8; j++) { r[j] = f2b(f[j]); m = fmaxf(m, fabsf(f[j])); }
        *(ushort8v*)(Ab + (size_t)row * AW + cg * 8) = r;
        #pragma unroll
        for (int off = 1; off < 16; off <<= 1) m = fmaxf(m, __shfl_xor(m, off));
        float scale = (m > 0.0f) ? 127.0f / m : 0.0f;
        int2 q = qpack(f, scale);
        *(int2*)(Q0 + (size_t)row * 128 + cg * 8) = q;
        if (cg == 0) rm0[row] = m * (1.0f / 127.0f);   // dinv folded in degcnt
    } else if (b < NB_E + NB_CVT + 2 * NB_WH) {
        int wi = b - NB_E - NB_CVT;
        const float* W = (wi < NB_WH) ? W0 : W1;
        unsigned short* Wfm = (wi < NB_WH) ? Wt0 : Wt1;
        int i = (wi % NB_WH) * 256 + tid;  // < 65536
        int j = i & 7, l = (i >> 3) & 63, kcl = (i >> 9) & 3, nt = (i >> 11) & 7, c = i >> 14;
        int r = kcl * 32 + (l >> 4) * 8 + j;
        int col = nt * 16 + (l & 15);
        Wfm[i] = f2b(W[((size_t)c * 128 + r) * 128 + col]);
    } else {
        int i = (b - NB_E - NB_CVT - 2 * NB_WH) * 256 + tid;  // < 32768
        int j = i & 7, l = (i >> 3) & 63, kcl = (i >> 9) & 3, nt = (i >> 11) & 7, half = (i >> 14) & 1;
        int k = kcl * 32 + (l >> 4) * 8 + j;
        int col = half * 128 + nt * 16 + (l & 15);
        int kcheb = col >> 6, cc = col & 63;
        float v = (cc < CLS) ? W2[((size_t)kcheb * 128 + k) * CLS + cc] : 0.0f;
        Wz[i] = f2b(v);
    }
}

// ---------------- scan over hist (length HL2) ----------------

__global__ void scanA_k(const int* __restrict__ hist, int* __restrict__ bsum) {
    __shared__ int lds[256];
    int base = blockIdx.x * SCAN_CHUNK;
    int s = 0;
    for (int j = threadIdx.x; j < SCAN_CHUNK; j += 256) {
        int i = base + j;
        if (i < HL2) s += hist[i];
    }
    lds[threadIdx.x] = s;
    __syncthreads();
    for (int off = 128; off > 0; off >>= 1) {
        if (threadIdx.x < off) lds[threadIdx.x] += lds[threadIdx.x + off];
        __syncthreads();
    }
    if (threadIdx.x == 0) bsum[blockIdx.x] = lds[0];
}

__global__ void scanB_k(int* bsum, int* scanned) {
    if (threadIdx.x == 0 && blockIdx.x == 0) {
        int run = 0;
        for (int b = 0; b < NB_S; b++) { int t = bsum[b]; bsum[b] = run; run += t; }
        scanned[HL2] = run;  // == 2*NE
    }
}

__global__ void scanC_k(const int* __restrict__ hist, const int* __restrict__ bsum,
                        int* __restrict__ scanned) {
    __shared__ int lds[256];
    int base = blockIdx.x * SCAN_CHUNK + threadIdx.x * 8;
    int v[8];
    int s = 0;
    #pragma unroll
    for (int j = 0; j < 8; j++) {
        int i = base + j;
        v[j] = (i < HL2) ? hist[i] : 0;
        s += v[j];
    }
    lds[threadIdx.x] = s;
    __syncthreads();
    for (int off = 1; off < 256; off <<= 1) {
        int t = (threadIdx.x >= (unsigned)off) ? lds[threadIdx.x - off] : 0;
        __syncthreads();
        lds[threadIdx.x] += t;
        __syncthreads();
    }
    int incl = lds[threadIdx.x];
    int excl = incl - s;
    int run = bsum[blockIdx.x] + excl;
    #pragma unroll
    for (int j = 0; j < 8; j++) {
        int i = base + j;
        if (i < HL2) scanned[i] = run;
        run += v[j];
    }
}

// ---------------- partition edges (LDS ranks, no global atomics) ----------------

__global__ __launch_bounds__(256) void part_k(const int4* __restrict__ esrc4,
                                              const int4* __restrict__ edst4,
                                              const int* __restrict__ scanned,
                                              int* __restrict__ ebuf,
                                              unsigned short* __restrict__ sbuf) {
    __shared__ int lcd[NBUK], lcs[NBUK];
    int b = blockIdx.x;
    int tid = threadIdx.x;
    for (int i = tid; i < NBUK; i += 256) { lcd[i] = 0; lcs[i] = 0; }
    __syncthreads();
    #pragma unroll
    for (int it = 0; it < 4; it++) {
        int u = b * EUNITS + it * 256 + tid;
        if (u < U4) {
            int4 s = esrc4[u], d = edst4[u];
            int dd[4] = {d.x, d.y, d.z, d.w};
            int ss[4] = {s.x, s.y, s.z, s.w};
            #pragma unroll
            for (int j = 0; j < 4; j++) {
                int bin = dd[j] >> BSH;
                int r = atomicAdd(&lcd[bin], 1);
                ebuf[scanned[bin * NB_E + b] + r] = ((dd[j] & (BINS - 1)) << 16) | ss[j];
                int sbin = ss[j] >> BSH;
                int r2 = atomicAdd(&lcs[sbin], 1);
                sbuf[scanned[HL + sbin * NB_E + b] + r2 - NE] = (unsigned short)(ss[j] & (BINS - 1));
            }
        }
    }
}

// ---------------- per-src-bucket degree -> dinv; fold dinv into dq0; phantom zeros ----------------

__global__ __launch_bounds__(256) void degcnt_k(const int* __restrict__ scanned,
                                                const unsigned short* __restrict__ sbuf,
                                                float* __restrict__ dinv,
                                                float* __restrict__ dqall) {
    __shared__ int cnt[BINS];
    int b = blockIdx.x;
    int tid = threadIdx.x;
    int s0 = scanned[HL + b * NB_E] - NE;
    int s1 = scanned[HL + (b + 1) * NB_E] - NE;
    if (tid < BINS) cnt[tid] = 0;
    __syncthreads();
    for (int e = s0 + tid; e < s1; e += 256)
        atomicAdd(&cnt[sbuf[e]], 1);
    __syncthreads();
    if (tid < BINS) {
        int node = b * BINS + tid;
        if (node < NN) {
            int d = cnt[tid];
            float dv = (d > 0) ? rsqrtf((float)d) : 0.0f;
            dinv[node] = dv;
            dqall[node] = dqall[node] * dv;   // dq0 = rm0 * dinv
        }
    }
    if (b == 0) {
        if (tid < 7) dqall[tid * (NN + 1) + NN] = 0.0f;   // phantom scales
        if (tid == 255) dinv[NN] = 0.0f;                  // phantom row weight
    }
}

// ---------------- per-bucket counting sort -> 32-aligned sentinel-padded CSR ----------------

__global__ __launch_bounds__(256) void bsort_k(const int* __restrict__ scanned,
                                               const int* __restrict__ ebuf,
                                               int* __restrict__ ews,
                                               int* __restrict__ rp,
                                               int* __restrict__ rpe) {
    __shared__ int cnt[BINS], excl[BINS], rnk[BINS];
    int b = blockIdx.x;
    int tid = threadIdx.x;
    int s0b = scanned[b * NB_E];
    int s1b = scanned[(b + 1) * NB_E];
    if (tid < BINS) { cnt[tid] = 0; rnk[tid] = 0; }
    __syncthreads();
    for (int e = s0b + tid; e < s1b; e += 256)
        atomicAdd(&cnt[ebuf[e] >> 16], 1);
    __syncthreads();
    if (tid == 0) {
        int run = 0;
        for (int i = 0; i < BINS; i++) { excl[i] = run; run += (cnt[i] + 31) & ~31; }
    }
    __syncthreads();
    int abase = (s0b + b * BSLACK + 31) & ~31;
    if (tid < BINS) {
        int node = b * BINS + tid;
        if (node < NN) {
            rp[node]  = abase + excl[tid];
            rpe[node] = abase + excl[tid] + ((cnt[tid] + 31) & ~31);
        }
    }
    for (int e = s0b + tid; e < s1b; e += 256) {
        int pk = ebuf[e];
        int low = pk >> 16;
        int pos = abase + excl[low] + atomicAdd(&rnk[low], 1);
        ews[pos] = pk & 0xFFFF;
    }
    for (int i = tid; i < BINS * 32; i += 256) {
        int bin = i >> 5;
        int off = cnt[bin] + (i & 31);
        if (off < ((cnt[bin] + 31) & ~31))
            ews[abase + excl[bin] + off] = NN;
    }
}

// ---------------- hquant: bf16 row (stride STRIDE) -> int8 row + dq table ----------------

template <int NL, int STRIDE>
__global__ __launch_bounds__(256) void hquant_k(const unsigned short* __restrict__ src,
                                                const float* __restrict__ dinv,
                                                signed char* __restrict__ Q,
                                                float* __restrict__ dqout) {
    int i = blockIdx.x * 256 + threadIdx.x;
    int row = i / NL, ln = i % NL;
    if (row >= NN) return;
    ushort8v u = *(const ushort8v*)(src + (size_t)row * STRIDE + ln * 8);
    float f[8];
    float m = 0.0f;
    #pragma unroll
    for (int j = 0; j < 8; j++) { f[j] = b2f(u[j]); m = fmaxf(m, fabsf(f[j])); }
    #pragma unroll
    for (int off = 1; off < NL; off <<= 1) m = fmaxf(m, __shfl_xor(m, off));
    float scale = (m > 0.0f) ? 127.0f / m : 0.0f;
    int2 q = qpack(f, scale);
    *(int2*)(Q + (size_t)row * (NL * 8) + ln * 8) = q;
    if (ln == 0) dqout[row] = dinv[row] * m * (1.0f / 127.0f);
}

// ---------------- SpMM 128-wide (hidden), int8 gather: 8 slots x 8 lanes, int4 loads ----
// 32 edges in flight per wave; branch-free padded CSR (pad 32).

template <bool CHEB>
__global__ __launch_bounds__(256) void spmm_k(const signed char* __restrict__ Qin,
                                              const float* __restrict__ dqin,
                                              const unsigned short* __restrict__ prevp,
                                              unsigned short* __restrict__ outp,
                                              signed char* __restrict__ Qout,
                                              float* __restrict__ dqout,
                                              const int* __restrict__ rp,
                                              const int* __restrict__ rpe,
                                              const int* __restrict__ ews,
                                              const float* __restrict__ dinv) {
    int row = blockIdx.x * 4 + (threadIdx.x >> 6);
    int lane = threadIdx.x & 63;
    int slot = lane >> 3, ln = lane & 7;   // 8 slots x 8 lanes
    int e0 = rp[row], e1 = rpe[row];
    float dvr = dinv[row];
    float acc[16];
    #pragma unroll
    for (int j = 0; j < 16; j++) acc[j] = 0.0f;
    for (int e = e0; e < e1; e += 32) {
        int4 s4 = *(const int4*)&ews[e + slot * 4];
        int4 q0 = *(const int4*)(Qin + (size_t)s4.x * 128 + ln * 16);
        int4 q1 = *(const int4*)(Qin + (size_t)s4.y * 128 + ln * 16);
        int4 q2 = *(const int4*)(Qin + (size_t)s4.z * 128 + ln * 16);
        int4 q3 = *(const int4*)(Qin + (size_t)s4.w * 128 + ln * 16);
        float w0 = -dqin[s4.x] * dvr, w1 = -dqin[s4.y] * dvr;
        float w2 = -dqin[s4.z] * dvr, w3 = -dqin[s4.w] * dvr;
        int a0[4] = {q0.x, q0.y, q0.z, q0.w};
        int a1[4] = {q1.x, q1.y, q1.z, q1.w};
        int a2[4] = {q2.x, q2.y, q2.z, q2.w};
        int a3[4] = {q3.x, q3.y, q3.z, q3.w};
        #pragma unroll
        for (int w = 0; w < 4; w++)
            #pragma unroll
            for (int j = 0; j < 4; j++)
                acc[w * 4 + j] += w0 * sb(a0[w], j) + w1 * sb(a1[w], j)
                                + w2 * sb(a2[w], j) + w3 * sb(a3[w], j);
    }
    #pragma unroll
    for (int j = 0; j < 16; j++) {
        acc[j] += __shfl_xor(acc[j], 8);
        acc[j] += __shfl_xor(acc[j], 16);
        acc[j] += __shfl_xor(acc[j], 32);
    }
    if (slot == 0) {
        // lane ln owns cols ln*16 .. ln*16+15
        float r[16];
        if (CHEB) {
            ushort8v p0 = *(const ushort8v*)(prevp + (size_t)row * AW + ln * 16);
            ushort8v p1 = *(const ushort8v*)(prevp + (size_t)row * AW + ln * 16 + 8);
            #pragma unroll
            for (int j = 0; j < 8; j++) {
                r[j]     = 2.f * acc[j]     - b2f(p0[j]);
                r[8 + j] = 2.f * acc[8 + j] - b2f(p1[j]);
            }
        } else {
            #pragma unroll
            for (int j = 0; j < 16; j++) r[j] = acc[j];
        }
        ushort8v o0, o1;
        float m = 0.0f;
        #pragma unroll
        for (int j = 0; j < 8; j++) {
            o0[j] = f2b(r[j]);     m = fmaxf(m, fabsf(r[j]));
            o1[j] = f2b(r[8 + j]); m = fmaxf(m, fabsf(r[8 + j]));
        }
        *(ushort8v*)(outp + (size_t)row * AW + ln * 16) = o0;
        *(ushort8v*)(outp + (size_t)row * AW + ln * 16 + 8) = o1;
        #pragma unroll
        for (int off = 1; off < 8; off <<= 1) m = fmaxf(m, __shfl_xor(m, off));
        float scale = (m > 0.0f) ? 127.0f / m : 0.0f;
        int2 qa = qpack(r, scale);
        int2 qb = qpack(r + 8, scale);
        int4 qq; qq.x = qa.x; qq.y = qa.y; qq.z = qb.x; qq.w = qb.y;
        *(int4*)(Qout + (size_t)row * 128 + ln * 16) = qq;
        if (ln == 0) dqout[row] = dvr * m * (1.0f / 127.0f);
    }
}

// ---------------- SpMM 64-wide Clenshaw, int8 gather: 16 slots x 4 lanes, int4 loads ----
// MODE 0: B2 = Z2 + 2*L(B3); MODE 1: B1 = Z1 + 2*L(B2) - Z3; MODE 2: out = lsm(Z0 + L(B1) - B2)

template <int MODE>
__global__ __launch_bounds__(256) void spmm64_k(const signed char* __restrict__ Qin,
                                                const float* __restrict__ dqin,
                                                const unsigned short* __restrict__ zadd,
                                                const unsigned short* __restrict__ bsub,
                                                unsigned short* __restrict__ wout,
                                                signed char* __restrict__ Qout,
                                                float* __restrict__ dqout,
                                                float* __restrict__ fout,
                                                const int* __restrict__ rp,
                                                const int* __restrict__ rpe,
                                                const int* __restrict__ ews,
                                                const float* __restrict__ dinv) {
    constexpr float SC = (MODE == 2) ? 1.0f : 2.0f;
    int row = blockIdx.x * 4 + (threadIdx.x >> 6);
    int lane = threadIdx.x & 63;
    int slot = lane >> 2, ln = lane & 3;   // 16 slots x 4 lanes
    int e0 = rp[row], e1 = rpe[row];
    float dvr = dinv[row];
    float acc[16];
    #pragma unroll
    for (int j = 0; j < 16; j++) acc[j] = 0.0f;
    for (int e = e0; e < e1; e += 32) {
        int2 s2 = *(const int2*)&ews[e + slot * 2];
        int4 q0 = *(const int4*)(Qin + (size_t)s2.x * 64 + ln * 16);
        int4 q1 = *(const int4*)(Qin + (size_t)s2.y * 64 + ln * 16);
        float w0 = -dqin[s2.x] * dvr, w1 = -dqin[s2.y] * dvr;
        int a0[4] = {q0.x, q0.y, q0.z, q0.w};
        int a1[4] = {q1.x, q1.y, q1.z, q1.w};
        #pragma unroll
        for (int w = 0; w < 4; w++)
            #pragma unroll
            for (int j = 0; j < 4; j++)
                acc[w * 4 + j] += w0 * sb(a0[w], j) + w1 * sb(a1[w], j);
    }
    #pragma unroll
    for (int j = 0; j < 16; j++) {
        acc[j] += __shfl_xor(acc[j], 4);
        acc[j] += __shfl_xor(acc[j], 8);
        acc[j] += __shfl_xor(acc[j], 16);
        acc[j] += __shfl_xor(acc[j], 32);
    }
    if (slot != 0) return;
    // lane ln owns cols ln*16 .. ln*16+15
    ushort8v z0 = *(const ushort8v*)(zadd + (size_t)row * ZW + ln * 16);
    ushort8v z1 = *(const ushort8v*)(zadd + (size_t)row * ZW + ln * 16 + 8);
    float v[16];
    if (MODE == 0) {
        #pragma unroll
        for (int j = 0; j < 8; j++) {
            v[j]     = b2f(z0[j]) + SC * acc[j];
            v[8 + j] = b2f(z1[j]) + SC * acc[8 + j];
        }
    } else {
        constexpr int BS = (MODE == 1) ? ZW : 64;
        ushort8v b0 = *(const ushort8v*)(bsub + (size_t)row * BS + ln * 16);
        ushort8v b1 = *(const ushort8v*)(bsub + (size_t)row * BS + ln * 16 + 8);
        #pragma unroll
        for (int j = 0; j < 8; j++) {
            v[j]     = b2f(z0[j]) + SC * acc[j]     - b2f(b0[j]);
            v[8 + j] = b2f(z1[j]) + SC * acc[8 + j] - b2f(b1[j]);
        }
    }
    if (MODE < 2) {
        ushort8v o0, o1;
        float m = 0.0f;
        #pragma unroll
        for (int j = 0; j < 8; j++) {
            o0[j] = f2b(v[j]);     m = fmaxf(m, fabsf(v[j]));
            o1[j] = f2b(v[8 + j]); m = fmaxf(m, fabsf(v[8 + j]));
        }
        *(ushort8v*)(wout + (size_t)row * 64 + ln * 16) = o0;
        *(ushort8v*)(wout + (size_t)row * 64 + ln * 16 + 8) = o1;
        #pragma unroll
        for (int off = 1; off < 4; off <<= 1) m = fmaxf(m, __shfl_xor(m, off));
        float scale = (m > 0.0f) ? 127.0f / m : 0.0f;
        int2 qa = qpack(v, scale);
        int2 qb = qpack(v + 8, scale);
        int4 qq; qq.x = qa.x; qq.y = qa.y; qq.z = qb.x; qq.w = qb.y;
        *(int4*)(Qout + (size_t)row * 64 + ln * 16) = qq;
        if (ln == 0) dqout[row] = dvr * m * (1.0f / 127.0f);
    } else {
        float m = -INFINITY;
        #pragma unroll
        for (int j = 0; j < 16; j++) if (ln * 16 + j < CLS) m = fmaxf(m, v[j]);
        #pragma unroll
        for (int off = 1; off < 4; off <<= 1) m = fmaxf(m, __shfl_xor(m, off));
        float s = 0.f;
        #pragma unroll
        for (int j = 0; j < 16; j++) if (ln * 16 + j < CLS) s += __expf(v[j] - m);
        #pragma unroll
        for (int off = 1; off < 4; off <<= 1) s += __shfl_xor(s, off);
        float ls = logf(s) + m;
        #pragma unroll
        for (int j = 0; j < 16; j++) {
            int col = ln * 16 + j;
            if (col < CLS) fout[(size_t)row * CLS + col] = v[j] - ls;
        }
    }
}

// ---------------- MFMA GEMM hidden: A[N x 512] @ W -> relu bf16 slice0 ----------------

__global__ __launch_bounds__(256) void gemm_hid_k(const unsigned short* __restrict__ A,
                                                  const unsigned short* __restrict__ Wfm,
                                                  const float* __restrict__ bias,
                                                  unsigned short* __restrict__ Hout) {
    __shared__ unsigned short Blds[16384];  // 32KB
    int tid = threadIdx.x;
    int w = tid >> 6, lane = tid & 63, ln = lane & 15, gp = lane >> 4;
    int rowbase = blockIdx.x * 64 + w * 16;
    int rowc = rowbase + ln;
    if (rowc >= NN) rowc = NN - 1;
    const unsigned short* Arow = A + (size_t)rowc * AW + gp * 8;

    f32x4 acc[8];
    #pragma unroll
    for (int i = 0; i < 8; i++) acc[i] = (f32x4){0.f, 0.f, 0.f, 0.f};

    short8v acur[4], anxt[4];
    #pragma unroll
    for (int kcl = 0; kcl < 4; kcl++) acur[kcl] = *(const short8v*)(Arow + kcl * 32);
    {
        const ushort8v* g = (const ushort8v*)Wfm;
        ushort8v* s = (ushort8v*)Blds;
        #pragma unroll
        for (int i = 0; i < 8; i++) s[tid + i * 256] = g[tid + i * 256];
    }
    __syncthreads();

    for (int c = 0; c < 4; c++) {
        if (c < 3) {
            #pragma unroll
            for (int kcl = 0; kcl < 4; kcl++)
                anxt[kcl] = *(const short8v*)(Arow + (c + 1) * 128 + kcl * 32);
        }
        #pragma unroll
        for (int kcl = 0; kcl < 4; kcl++) {
            #pragma unroll
            for (int nt = 0; nt < 8; nt++) {
                short8v b = *(const short8v*)&Blds[((nt * 4 + kcl) * 64 + lane) * 8];
                acc[nt] = __builtin_amdgcn_mfma_f32_16x16x32_bf16(acur[kcl], b, acc[nt], 0, 0, 0);
            }
        }
        if (c < 3) {
            __syncthreads();
            const ushort8v* g = (const ushort8v*)(Wfm + (c + 1) * 16384);
            ushort8v* s = (ushort8v*)Blds;
            #pragma unroll
            for (int i = 0; i < 8; i++) s[tid + i * 256] = g[tid + i * 256];
            __syncthreads();
            #pragma unroll
            for (int kcl = 0; kcl < 4; kcl++) acur[kcl] = anxt[kcl];
        }
    }

    if (rowbase < NN) {
        #pragma unroll
        for (int nt = 0; nt < 8; nt++) {
            int col = nt * 16 + ln;
            float bv = bias[col];
            #pragma unroll
            for (int j = 0; j < 4; j++) {
                int r = rowbase + gp * 4 + j;
                Hout[(size_t)r * AW + col] = f2b(fmaxf(acc[nt][j] + bv, 0.0f));
            }
        }
    }
}

// ---------------- MFMA GEMM Z: h[N x 128] @ Wcat[128 x 256] -> Z bf16 (+compact Z3) ----

__global__ __launch_bounds__(256) void gemm_z_k(const unsigned short* __restrict__ A,
                                                const unsigned short* __restrict__ Wz,
                                                const float* __restrict__ b2,
                                                unsigned short* __restrict__ Z,
                                                unsigned short* __restrict__ B3c) {
    __shared__ unsigned short Blds[16384];
    int tid = threadIdx.x;
    int w = tid >> 6, lane = tid & 63, ln = lane & 15, gp = lane >> 4;
    int rowbase = blockIdx.x * 64 + w * 16;
    int rowc = rowbase + ln;
    if (rowc >= NN) rowc = NN - 1;
    const unsigned short* Arow = A + (size_t)rowc * AW + gp * 8;

    short8v af[4];
    #pragma unroll
    for (int kcl = 0; kcl < 4; kcl++) af[kcl] = *(const short8v*)(Arow + kcl * 32);

    for (int half = 0; half < 2; half++) {
        if (half) __syncthreads();
        {
            const ushort8v* g = (const ushort8v*)(Wz + half * 16384);
            ushort8v* s = (ushort8v*)Blds;
            #pragma unroll
            for (int i = 0; i < 8; i++) s[tid + i * 256] = g[tid + i * 256];
        }
        __syncthreads();
        f32x4 acc[8];
        #pragma unroll
        for (int i = 0; i < 8; i++) acc[i] = (f32x4){0.f, 0.f, 0.f, 0.f};
        #pragma unroll
        for (int kcl = 0; kcl < 4; kcl++) {
            #pragma unroll
            for (int nt = 0; nt < 8; nt++) {
                short8v b = *(const short8v*)&Blds[((nt * 4 + kcl) * 64 + lane) * 8];
                acc[nt] = __builtin_amdgcn_mfma_f32_16x16x32_bf16(af[kcl], b, acc[nt], 0, 0, 0);
            }
        }
        if (rowbase < NN) {
            #pragma unroll
            for (int nt = 0; nt < 8; nt++) {
                int col = half * 128 + nt * 16 + ln;
                float bv = (col < CLS) ? b2[col] : 0.0f;
                #pragma unroll
                for (int j = 0; j < 4; j++) {
                    int r = rowbase + gp * 4 + j;
                    unsigned short hv = f2b(acc[nt][j] + bv);
                    Z[(size_t)r * ZW + col] = hv;
                    if (half == 1 && nt >= 4) B3c[(size_t)r * 64 + (col - 192)] = hv;
                }
            }
        }
    }
}

// ---------------- launch ----------------

extern "C" void kernel_launch(void* const* d_in, const int* in_sizes, int n_in,
                              void* d_out, int out_size, void* d_ws, size_t ws_size,
                              hipStream_t stream) {
    const float* x    = (const float*)d_in[0];
    const int*   esrc = (const int*)d_in[1];
    const int*   edst = (const int*)d_in[2];
    const float* W0   = (const float*)d_in[3];
    const float* b0   = (const float*)d_in[4];
    const float* W1   = (const float*)d_in[5];
    const float* b1   = (const float*)d_in[6];
    const float* W2   = (const float*)d_in[7];
    const float* b2   = (const float*)d_in[8];
    float* out = (float*)d_out;

    char* p = (char*)d_ws;
    auto alloc = [&](size_t bytes) -> void* {
        void* r = (void*)p;
        p += (bytes + 255) & ~(size_t)255;
        return r;
    };
    unsigned short* Abuf = (unsigned short*)alloc((size_t)(NN + 1) * AW * 2);
    unsigned short* Zbuf = (unsigned short*)alloc((size_t)NN * ZW * 2);
    unsigned short* B1b  = (unsigned short*)alloc((size_t)(NN + 1) * 64 * 2);
    unsigned short* B2b  = (unsigned short*)alloc((size_t)(NN + 1) * 64 * 2);
    unsigned short* B3b  = (unsigned short*)alloc((size_t)(NN + 1) * 64 * 2);
    signed char* Qb = (signed char*)alloc((size_t)4 * (NN + 1) * 128);
    signed char* Qc = (signed char*)alloc((size_t)3 * (NN + 1) * 64);
    float* dqall = (float*)alloc((size_t)7 * (NN + 1) * 4);
    int*   ews     = (int*)alloc((size_t)(NE + NBUK * BSLACK + 64) * 4);
    int*   ebuf    = (int*)alloc((size_t)NE * 4);
    unsigned short* sbuf = (unsigned short*)alloc((size_t)NE * 2);
    int*   hist    = (int*)alloc((size_t)HL2 * 4);
    int*   scanned = (int*)alloc((size_t)(HL2 + 1) * 4);
    int*   bsum    = (int*)alloc(NB_S * 4);
    unsigned short* Wt0 = (unsigned short*)alloc((size_t)128 * AW * 2);
    unsigned short* Wt1 = (unsigned short*)alloc((size_t)128 * AW * 2);
    unsigned short* Wz  = (unsigned short*)alloc((size_t)32768 * 2);
    int*   rp   = (int*)alloc(NN * 4);
    int*   rpe  = (int*)alloc(NN * 4);
    float* dinv = (float*)alloc((NN + 1) * 4);

    signed char* Q0 = Qb;
    signed char* Q1 = Qb + (size_t)1 * (NN + 1) * 128;
    signed char* Q2 = Qb + (size_t)2 * (NN + 1) * 128;
    signed char* Q3 = Qb + (size_t)3 * (NN + 1) * 128;
    signed char* Qc3 = Qc;
    signed char* Qc2 = Qc + (size_t)1 * (NN + 1) * 64;
    signed char* Qc1 = Qc + (size_t)2 * (NN + 1) * 64;
    float* dq0 = dqall;
    float* dq1 = dqall + 1 * (NN + 1);
    float* dq2 = dqall + 2 * (NN + 1);
    float* dq3 = dqall + 3 * (NN + 1);
    float* dqc3 = dqall + 4 * (NN + 1);
    float* dqc2 = dqall + 5 * (NN + 1);
    float* dqc1 = dqall + 6 * (NN + 1);

    const int TB = 256;

    prep_k<<<NB_E + NB_CVT + 2 * NB_WH + NB_WZ, TB, 0, stream>>>(
        (const int4*)esrc, (const int4*)edst, hist,
        x, Abuf, Q0, dq0, W0, W1, W2, Wt0, Wt1, Wz);
    scanA_k<<<NB_S, TB, 0, stream>>>(hist, bsum);
    scanB_k<<<1, 64, 0, stream>>>(bsum, scanned);
    scanC_k<<<NB_S, TB, 0, stream>>>(hist, bsum, scanned);
    part_k<<<NB_E, TB, 0, stream>>>((const int4*)esrc, (const int4*)edst, scanned, ebuf, sbuf);
    degcnt_k<<<NBUK, TB, 0, stream>>>(scanned, sbuf, dinv, dqall);
    bsort_k<<<NBUK, TB, 0, stream>>>(scanned, ebuf, ews, rp, rpe);

    int gSpmm = (NN + 3) / 4;        // 12500
    int gGemm = (NN + 63) / 64;      // 782
    int gHq128 = NN * 16 / TB;       // 3125
    int gHq64  = (NN * 8 + TB - 1) / TB;   // 1563

    unsigned short* s0 = Abuf + 0 * 128;
    unsigned short* s1 = Abuf + 1 * 128;
    unsigned short* s2 = Abuf + 2 * 128;
    unsigned short* s3 = Abuf + 3 * 128;

    for (int l = 0; l < 2; l++) {
        spmm_k<false><<<gSpmm, TB, 0, stream>>>(Q0, dq0, nullptr, s1, Q1, dq1, rp, rpe, ews, dinv);
        spmm_k<true><<<gSpmm, TB, 0, stream>>>(Q1, dq1, s0, s2, Q2, dq2, rp, rpe, ews, dinv);
        spmm_k<true><<<gSpmm, TB, 0, stream>>>(Q2, dq2, s1, s3, Q3, dq3, rp, rpe, ews, dinv);
        const unsigned short* Wt = (l == 0) ? Wt0 : Wt1;
        const float* bl = (l == 0) ? b0 : b1;
        gemm_hid_k<<<gGemm, TB, 0, stream>>>(Abuf, Wt, bl, Abuf);  // relu'd h -> slice0
        hquant_k<16, AW><<<gHq128, TB, 0, stream>>>(s0, dinv, Q0, dq0);
    }

    // last layer: Z = h @ Wcat (+bias on Z0, compact Z3), then int8 Clenshaw
    gemm_z_k<<<gGemm, TB, 0, stream>>>(Abuf, Wz, b2, Zbuf, B3b);
    hquant_k<8, 64><<<gHq64, TB, 0, stream>>>(B3b, dinv, Qc3, dqc3);
    spmm64_k<0><<<gSpmm, TB, 0, stream>>>(Qc3, dqc3, Zbuf + 128, nullptr,
                                          B2b, Qc2, dqc2, nullptr, rp, rpe, ews, dinv);
    spmm64_k<1><<<gSpmm, TB, 0, stream>>>(Qc2, dqc2, Zbuf + 64, Zbuf + 192,
                                          B1b, Qc1, dqc1, nullptr, rp, rpe, ews, dinv);
    spmm64_k<2><<<gSpmm, TB, 0, stream>>>(Qc1, dqc1, Zbuf, B2b,
                                          nullptr, nullptr, nullptr, out, rp, rpe, ews, dinv);
}

// Round 18
// 366.036 us; speedup vs baseline: 1.3594x; 1.3594x over previous
//
#include <hip/hip_runtime.h>
#include <math.h>

#define NN 50000
#define NE 800000
#define FDIM 128
#define CLS 40
#define AW 512    // hidden A width: 4 Chebyshev slices of 128
#define ZW 256    // last-layer Z width: 4 slices of 64 (40 used)

// CSR-by-bucket-sort parameters
#define BSH 7
#define BINS 128                  // nodes per bucket
#define NBUK 391                  // ceil(NN/128)
#define NB_E 196                  // edge-chunk blocks (hist & partition)
#define EUNITS 1024               // int4 units per edge block
#define U4 (NE / 4)               // 200000
#define HL (NBUK * NB_E)          // 76636
#define HL2 (2 * HL)
#define SCAN_CHUNK 2048
#define NB_S ((HL2 + SCAN_CHUNK - 1) / SCAN_CHUNK)   // 75
#define BSLACK 4096               // per-bucket padding slack (>= 128*31 + 31)

typedef __attribute__((ext_vector_type(8))) short short8v;
typedef __attribute__((ext_vector_type(8))) unsigned short ushort8v;
typedef __attribute__((ext_vector_type(4))) float f32x4;

__device__ inline float b2f(unsigned short u) {
    union { unsigned int i; float f; } v; v.i = ((unsigned)u) << 16; return v.f;
}
__device__ inline unsigned short f2b(float f) {
    unsigned int x = __float_as_uint(f);
    unsigned int r = (x + 0x7fffu + ((x >> 16) & 1u)) >> 16;
    return (unsigned short)r;
}

// ---------------- fused prep: [dual-hist | cvtx | wprep0 | wprep1 | wprep_z] ----------------
#define NB_CVT  3125
#define NB_WH   256
#define NB_WZ   128

__global__ __launch_bounds__(256) void prep_k(
        const int4* __restrict__ esrc4, const int4* __restrict__ edst4,
        int* __restrict__ hist,
        const float* __restrict__ x, unsigned short* __restrict__ Ab,
        const float* __restrict__ W0, const float* __restrict__ W1,
        const float* __restrict__ W2,
        unsigned short* __restrict__ Wt0, unsigned short* __restrict__ Wt1,
        unsigned short* __restrict__ Wz) {
    int b = blockIdx.x;
    int tid = threadIdx.x;
    if (b < NB_E) {
        __shared__ int lcd[NBUK], lcs[NBUK];
        for (int i = tid; i < NBUK; i += 256) { lcd[i] = 0; lcs[i] = 0; }
        __syncthreads();
        #pragma unroll
        for (int it = 0; it < 4; it++) {
            int u = b * EUNITS + it * 256 + tid;
            if (u < U4) {
                int4 s = esrc4[u], d = edst4[u];
                atomicAdd(&lcd[d.x >> BSH], 1); atomicAdd(&lcd[d.y >> BSH], 1);
                atomicAdd(&lcd[d.z >> BSH], 1); atomicAdd(&lcd[d.w >> BSH], 1);
                atomicAdd(&lcs[s.x >> BSH], 1); atomicAdd(&lcs[s.y >> BSH], 1);
                atomicAdd(&lcs[s.z >> BSH], 1); atomicAdd(&lcs[s.w >> BSH], 1);
            }
        }
        __syncthreads();
        for (int i = tid; i < NBUK; i += 256) {
            hist[i * NB_E + b] = lcd[i];
            hist[HL + i * NB_E + b] = lcs[i];
        }
    } else if (b < NB_E + NB_CVT) {
        int i = (b - NB_E) * 256 + tid;   // < NN*16
        int row = i >> 4, cg = i & 15;
        const float4* xp = (const float4*)(x + (size_t)row * FDIM + cg * 8);
        float4 v0 = xp[0], v1 = xp[1];
        ushort8v r;
        r[0] = f2b(v0.x); r[1] = f2b(v0.y); r[2] = f2b(v0.z); r[3] = f2b(v0.w);
        r[4] = f2b(v1.x); r[5] = f2b(v1.y); r[6] = f2b(v1.z); r[7] = f2b(v1.w);
        *(ushort8v*)(Ab + (size_t)row * AW + cg * 8) = r;
    } else if (b < NB_E + NB_CVT + 2 * NB_WH) {
        int wi = b - NB_E - NB_CVT;
        const float* W = (wi < NB_WH) ? W0 : W1;
        unsigned short* Wfm = (wi < NB_WH) ? Wt0 : Wt1;
        int i = (wi % NB_WH) * 256 + tid;  // < 65536
        int j = i & 7, l = (i >> 3) & 63, kcl = (i >> 9) & 3, nt = (i >> 11) & 7, c = i >> 14;
        int r = kcl * 32 + (l >> 4) * 8 + j;
        int col = nt * 16 + (l & 15);
        Wfm[i] = f2b(W[((size_t)c * 128 + r) * 128 + col]);
    } else {
        int i = (b - NB_E - NB_CVT - 2 * NB_WH) * 256 + tid;  // < 32768
        int j = i & 7, l = (i >> 3) & 63, kcl = (i >> 9) & 3, nt = (i >> 11) & 7, half = (i >> 14) & 1;
        int k = kcl * 32 + (l >> 4) * 8 + j;
        int col = half * 128 + nt * 16 + (l & 15);
        int kcheb = col >> 6, cc = col & 63;
        float v = (cc < CLS) ? W2[((size_t)kcheb * 128 + k) * CLS + cc] : 0.0f;
        Wz[i] = f2b(v);
    }
}

// ---------------- scan over hist (length HL2) -> scanned (exclusive, +total at [HL2]) ----------------

__global__ void scanA_k(const int* __restrict__ hist, int* __restrict__ bsum) {
    __shared__ int lds[256];
    int base = blockIdx.x * SCAN_CHUNK;
    int s = 0;
    for (int j = threadIdx.x; j < SCAN_CHUNK; j += 256) {
        int i = base + j;
        if (i < HL2) s += hist[i];
    }
    lds[threadIdx.x] = s;
    __syncthreads();
    for (int off = 128; off > 0; off >>= 1) {
        if (threadIdx.x < off) lds[threadIdx.x] += lds[threadIdx.x + off];
        __syncthreads();
    }
    if (threadIdx.x == 0) bsum[blockIdx.x] = lds[0];
}

__global__ void scanB_k(int* bsum, int* scanned) {
    if (threadIdx.x == 0 && blockIdx.x == 0) {
        int run = 0;
        for (int b = 0; b < NB_S; b++) { int t = bsum[b]; bsum[b] = run; run += t; }
        scanned[HL2] = run;  // == 2*NE
    }
}

__global__ void scanC_k(const int* __restrict__ hist, const int* __restrict__ bsum,
                        int* __restrict__ scanned) {
    __shared__ int lds[256];
    int base = blockIdx.x * SCAN_CHUNK + threadIdx.x * 8;
    int v[8];
    int s = 0;
    #pragma unroll
    for (int j = 0; j < 8; j++) {
        int i = base + j;
        v[j] = (i < HL2) ? hist[i] : 0;
        s += v[j];
    }
    lds[threadIdx.x] = s;
    __syncthreads();
    for (int off = 1; off < 256; off <<= 1) {
        int t = (threadIdx.x >= (unsigned)off) ? lds[threadIdx.x - off] : 0;
        __syncthreads();
        lds[threadIdx.x] += t;
        __syncthreads();
    }
    int incl = lds[threadIdx.x];
    int excl = incl - s;
    int run = bsum[blockIdx.x] + excl;
    #pragma unroll
    for (int j = 0; j < 8; j++) {
        int i = base + j;
        if (i < HL2) scanned[i] = run;
        run += v[j];
    }
}

// ---------------- partition edges: dst-packed ebuf + src-low sbuf (LDS ranks) ----------------

__global__ __launch_bounds__(256) void part_k(const int4* __restrict__ esrc4,
                                              const int4* __restrict__ edst4,
                                              const int* __restrict__ scanned,
                                              int* __restrict__ ebuf,
                                              unsigned short* __restrict__ sbuf) {
    __shared__ int lcd[NBUK], lcs[NBUK];
    int b = blockIdx.x;
    int tid = threadIdx.x;
    for (int i = tid; i < NBUK; i += 256) { lcd[i] = 0; lcs[i] = 0; }
    __syncthreads();
    #pragma unroll
    for (int it = 0; it < 4; it++) {
        int u = b * EUNITS + it * 256 + tid;
        if (u < U4) {
            int4 s = esrc4[u], d = edst4[u];
            int dd[4] = {d.x, d.y, d.z, d.w};
            int ss[4] = {s.x, s.y, s.z, s.w};
            #pragma unroll
            for (int j = 0; j < 4; j++) {
                int bin = dd[j] >> BSH;
                int r = atomicAdd(&lcd[bin], 1);
                ebuf[scanned[bin * NB_E + b] + r] = ((dd[j] & (BINS - 1)) << 16) | ss[j];
                int sbin = ss[j] >> BSH;
                int r2 = atomicAdd(&lcs[sbin], 1);
                sbuf[scanned[HL + sbin * NB_E + b] + r2 - NE] = (unsigned short)(ss[j] & (BINS - 1));
            }
        }
    }
}

// ---------------- per-src-bucket degree count -> dinv (atomic-free global) ----------------

__global__ __launch_bounds__(256) void degcnt_k(const int* __restrict__ scanned,
                                                const unsigned short* __restrict__ sbuf,
                                                float* __restrict__ dinv) {
    __shared__ int cnt[BINS];
    int b = blockIdx.x;
    int tid = threadIdx.x;
    int s0 = scanned[HL + b * NB_E] - NE;
    int s1 = scanned[HL + (b + 1) * NB_E] - NE;   // b==NBUK-1 -> scanned[HL2]-NE == NE
    if (tid < BINS) cnt[tid] = 0;
    __syncthreads();
    for (int e = s0 + tid; e < s1; e += 256)
        atomicAdd(&cnt[sbuf[e]], 1);
    __syncthreads();
    if (tid < BINS) {
        int node = b * BINS + tid;
        if (node < NN) {
            int d = cnt[tid];
            dinv[node] = (d > 0) ? rsqrtf((float)d) : 0.0f;
        }
    }
    if (b == 0 && tid == 255) dinv[NN] = 0.0f;   // phantom row weight
}

// ---------------- per-bucket counting sort -> 32-aligned sentinel-padded CSR ----------------

__global__ __launch_bounds__(256) void bsort_k(const int* __restrict__ scanned,
                                               const int* __restrict__ ebuf,
                                               int* __restrict__ ews,
                                               int* __restrict__ rp,
                                               int* __restrict__ rpe) {
    __shared__ int cnt[BINS], excl[BINS], rnk[BINS];
    int b = blockIdx.x;
    int tid = threadIdx.x;
    int s0b = scanned[b * NB_E];
    int s1b = scanned[(b + 1) * NB_E];   // b == NBUK-1 -> scanned[HL] == NE
    if (tid < BINS) { cnt[tid] = 0; rnk[tid] = 0; }
    __syncthreads();
    for (int e = s0b + tid; e < s1b; e += 256)
        atomicAdd(&cnt[ebuf[e] >> 16], 1);
    __syncthreads();
    if (tid == 0) {
        int run = 0;
        for (int i = 0; i < BINS; i++) { excl[i] = run; run += (cnt[i] + 31) & ~31; }
    }
    __syncthreads();
    int abase = (s0b + b * BSLACK + 31) & ~31;
    if (tid < BINS) {
        int node = b * BINS + tid;
        if (node < NN) {
            rp[node]  = abase + excl[tid];
            rpe[node] = abase + excl[tid] + ((cnt[tid] + 31) & ~31);
        }
    }
    for (int e = s0b + tid; e < s1b; e += 256) {
        int pk = ebuf[e];
        int low = pk >> 16;
        int pos = abase + excl[low] + atomicAdd(&rnk[low], 1);
        ews[pos] = pk & 0xFFFF;
    }
    // sentinel tails (pad region <= 31 per bin; disjoint from data writes)
    for (int i = tid; i < BINS * 32; i += 256) {
        int bin = i >> 5;
        int off = cnt[bin] + (i & 31);
        if (off < ((cnt[bin] + 31) & ~31))
            ews[abase + excl[bin] + off] = NN;
    }
}

// ---------------- SpMM 128-wide (hidden layers), branch-free padded CSR ----------------

template <bool CHEB>
__global__ __launch_bounds__(256) void spmm_k(const unsigned short* __restrict__ inp,
                                              const unsigned short* __restrict__ prevp,
                                              unsigned short* __restrict__ outp,
                                              const int* __restrict__ rp,
                                              const int* __restrict__ rpe,
                                              const int* __restrict__ ews,
                                              const float* __restrict__ dinv) {
    int row = blockIdx.x * 4 + (threadIdx.x >> 6);
    int lane = threadIdx.x & 63;
    int slot = lane >> 4, ln = lane & 15;
    int e0 = rp[row], e1 = rpe[row];
    float dvr = dinv[row];
    float acc[8] = {0.f, 0.f, 0.f, 0.f, 0.f, 0.f, 0.f, 0.f};
    for (int e = e0; e < e1; e += 16) {
        int4 s4 = *(const int4*)&ews[e + slot * 4];
        ushort8v t0 = *(const ushort8v*)(inp + (size_t)s4.x * AW + ln * 8);
        ushort8v t1 = *(const ushort8v*)(inp + (size_t)s4.y * AW + ln * 8);
        ushort8v t2 = *(const ushort8v*)(inp + (size_t)s4.z * AW + ln * 8);
        ushort8v t3 = *(const ushort8v*)(inp + (size_t)s4.w * AW + ln * 8);
        float w0 = -dinv[s4.x] * dvr, w1 = -dinv[s4.y] * dvr;
        float w2 = -dinv[s4.z] * dvr, w3 = -dinv[s4.w] * dvr;
        #pragma unroll
        for (int j = 0; j < 8; j++)
            acc[j] += w0 * b2f(t0[j]) + w1 * b2f(t1[j]) + w2 * b2f(t2[j]) + w3 * b2f(t3[j]);
    }
    #pragma unroll
    for (int j = 0; j < 8; j++) {
        acc[j] += __shfl_xor(acc[j], 16);
        acc[j] += __shfl_xor(acc[j], 32);
    }
    if (slot == 0) {
        ushort8v r;
        if (CHEB) {
            ushort8v p = *(const ushort8v*)(prevp + (size_t)row * AW + ln * 8);
            #pragma unroll
            for (int j = 0; j < 8; j++) r[j] = f2b(2.f * acc[j] - b2f(p[j]));
        } else {
            #pragma unroll
            for (int j = 0; j < 8; j++) r[j] = f2b(acc[j]);
        }
        *(ushort8v*)(outp + (size_t)row * AW + ln * 8) = r;
    }
}

// ---------------- SpMM 64-wide Clenshaw (last layer), branch-free padded CSR ----------------
// MODE 0: B2 = Z2 + 2*L(B3c); MODE 1: B1 = Z1 + 2*L(B2) - Z3; MODE 2: out = lsm(Z0 + L(B1) - B2)

template <int MODE>
__global__ __launch_bounds__(256) void spmm64_k(const unsigned short* __restrict__ gsrc,
                                                const unsigned short* __restrict__ zadd,
                                                const unsigned short* __restrict__ bsub,
                                                unsigned short* __restrict__ wout,
                                                float* __restrict__ fout,
                                                const int* __restrict__ rp,
                                                const int* __restrict__ rpe,
                                                const int* __restrict__ ews,
                                                const float* __restrict__ dinv) {
    constexpr float SC = (MODE == 2) ? 1.0f : 2.0f;
    int row = blockIdx.x * 4 + (threadIdx.x >> 6);
    int lane = threadIdx.x & 63;
    int slot = lane >> 3, ln = lane & 7;
    int e0 = rp[row], e1 = rpe[row];
    float dvr = dinv[row];
    float acc[8] = {0.f, 0.f, 0.f, 0.f, 0.f, 0.f, 0.f, 0.f};
    for (int e = e0; e < e1; e += 32) {
        int4 s4 = *(const int4*)&ews[e + slot * 4];
        ushort8v t0 = *(const ushort8v*)(gsrc + (size_t)s4.x * 64 + ln * 8);
        ushort8v t1 = *(const ushort8v*)(gsrc + (size_t)s4.y * 64 + ln * 8);
        ushort8v t2 = *(const ushort8v*)(gsrc + (size_t)s4.z * 64 + ln * 8);
        ushort8v t3 = *(const ushort8v*)(gsrc + (size_t)s4.w * 64 + ln * 8);
        float w0 = -dinv[s4.x] * dvr, w1 = -dinv[s4.y] * dvr;
        float w2 = -dinv[s4.z] * dvr, w3 = -dinv[s4.w] * dvr;
        #pragma unroll
        for (int j = 0; j < 8; j++)
            acc[j] += w0 * b2f(t0[j]) + w1 * b2f(t1[j]) + w2 * b2f(t2[j]) + w3 * b2f(t3[j]);
    }
    #pragma unroll
    for (int j = 0; j < 8; j++) {
        acc[j] += __shfl_xor(acc[j], 8);
        acc[j] += __shfl_xor(acc[j], 16);
        acc[j] += __shfl_xor(acc[j], 32);
    }
    if (slot != 0) return;
    ushort8v zv = *(const ushort8v*)(zadd + (size_t)row * ZW + ln * 8);
    float v[8];
    if (MODE == 0) {
        #pragma unroll
        for (int j = 0; j < 8; j++) v[j] = b2f(zv[j]) + SC * acc[j];
    } else {
        constexpr int BS = (MODE == 1) ? ZW : 64;
        ushort8v bv = *(const ushort8v*)(bsub + (size_t)row * BS + ln * 8);
        #pragma unroll
        for (int j = 0; j < 8; j++) v[j] = b2f(zv[j]) + SC * acc[j] - b2f(bv[j]);
    }
    if (MODE < 2) {
        ushort8v r;
        #pragma unroll
        for (int j = 0; j < 8; j++) r[j] = f2b(v[j]);
        *(ushort8v*)(wout + (size_t)row * 64 + ln * 8) = r;
    } else {
        float m = -INFINITY;
        #pragma unroll
        for (int j = 0; j < 8; j++) if (ln * 8 + j < CLS) m = fmaxf(m, v[j]);
        #pragma unroll
        for (int off = 4; off >= 1; off >>= 1) m = fmaxf(m, __shfl_xor(m, off));
        float s = 0.f;
        #pragma unroll
        for (int j = 0; j < 8; j++) if (ln * 8 + j < CLS) s += __expf(v[j] - m);
        #pragma unroll
        for (int off = 4; off >= 1; off >>= 1) s += __shfl_xor(s, off);
        float ls = logf(s) + m;
        #pragma unroll
        for (int j = 0; j < 8; j++) {
            int col = ln * 8 + j;
            if (col < CLS) fout[(size_t)row * CLS + col] = v[j] - ls;
        }
    }
}

// ---------------- MFMA GEMM hidden: A[N x 512] @ W -> relu bf16 slice0 ----------------

__global__ __launch_bounds__(256) void gemm_hid_k(const unsigned short* __restrict__ A,
                                                  const unsigned short* __restrict__ Wfm,
                                                  const float* __restrict__ bias,
                                                  unsigned short* __restrict__ Hout) {
    __shared__ unsigned short Blds[16384];  // 32KB
    int tid = threadIdx.x;
    int w = tid >> 6, lane = tid & 63, ln = lane & 15, gp = lane >> 4;
    int rowbase = blockIdx.x * 64 + w * 16;
    int rowc = rowbase + ln;
    if (rowc >= NN) rowc = NN - 1;  // clamp; never early-return (barriers)
    const unsigned short* Arow = A + (size_t)rowc * AW + gp * 8;

    f32x4 acc[8];
    #pragma unroll
    for (int i = 0; i < 8; i++) acc[i] = (f32x4){0.f, 0.f, 0.f, 0.f};

    short8v acur[4], anxt[4];
    #pragma unroll
    for (int kcl = 0; kcl < 4; kcl++) acur[kcl] = *(const short8v*)(Arow + kcl * 32);
    {
        const ushort8v* g = (const ushort8v*)Wfm;
        ushort8v* s = (ushort8v*)Blds;
        #pragma unroll
        for (int i = 0; i < 8; i++) s[tid + i * 256] = g[tid + i * 256];
    }
    __syncthreads();

    for (int c = 0; c < 4; c++) {
        if (c < 3) {
            #pragma unroll
            for (int kcl = 0; kcl < 4; kcl++)
                anxt[kcl] = *(const short8v*)(Arow + (c + 1) * 128 + kcl * 32);
        }
        #pragma unroll
        for (int kcl = 0; kcl < 4; kcl++) {
            #pragma unroll
            for (int nt = 0; nt < 8; nt++) {
                short8v b = *(const short8v*)&Blds[((nt * 4 + kcl) * 64 + lane) * 8];
                acc[nt] = __builtin_amdgcn_mfma_f32_16x16x32_bf16(acur[kcl], b, acc[nt], 0, 0, 0);
            }
        }
        if (c < 3) {
            __syncthreads();
            const ushort8v* g = (const ushort8v*)(Wfm + (c + 1) * 16384);
            ushort8v* s = (ushort8v*)Blds;
            #pragma unroll
            for (int i = 0; i < 8; i++) s[tid + i * 256] = g[tid + i * 256];
            __syncthreads();
            #pragma unroll
            for (int kcl = 0; kcl < 4; kcl++) acur[kcl] = anxt[kcl];
        }
    }

    if (rowbase < NN) {
        #pragma unroll
        for (int nt = 0; nt < 8; nt++) {
            int col = nt * 16 + ln;
            float bv = bias[col];
            #pragma unroll
            for (int j = 0; j < 4; j++) {
                int r = rowbase + gp * 4 + j;
                Hout[(size_t)r * AW + col] = f2b(fmaxf(acc[nt][j] + bv, 0.0f));
            }
        }
    }
}

// ---------------- MFMA GEMM Z: h[N x 128] @ Wcat[128 x 256] -> Z bf16 (+compact Z3 copy) ----

__global__ __launch_bounds__(256) void gemm_z_k(const unsigned short* __restrict__ A,
                                                const unsigned short* __restrict__ Wz,
                                                const float* __restrict__ b2,
                                                unsigned short* __restrict__ Z,
                                                unsigned short* __restrict__ B3c) {
    __shared__ unsigned short Blds[16384];  // 32KB per N-half
    int tid = threadIdx.x;
    int w = tid >> 6, lane = tid & 63, ln = lane & 15, gp = lane >> 4;
    int rowbase = blockIdx.x * 64 + w * 16;
    int rowc = rowbase + ln;
    if (rowc >= NN) rowc = NN - 1;
    const unsigned short* Arow = A + (size_t)rowc * AW + gp * 8;

    short8v af[4];
    #pragma unroll
    for (int kcl = 0; kcl < 4; kcl++) af[kcl] = *(const short8v*)(Arow + kcl * 32);

    for (int half = 0; half < 2; half++) {
        if (half) __syncthreads();
        {
            const ushort8v* g = (const ushort8v*)(Wz + half * 16384);
            ushort8v* s = (ushort8v*)Blds;
            #pragma unroll
            for (int i = 0; i < 8; i++) s[tid + i * 256] = g[tid + i * 256];
        }
        __syncthreads();
        f32x4 acc[8];
        #pragma unroll
        for (int i = 0; i < 8; i++) acc[i] = (f32x4){0.f, 0.f, 0.f, 0.f};
        #pragma unroll
        for (int kcl = 0; kcl < 4; kcl++) {
            #pragma unroll
            for (int nt = 0; nt < 8; nt++) {
                short8v b = *(const short8v*)&Blds[((nt * 4 + kcl) * 64 + lane) * 8];
                acc[nt] = __builtin_amdgcn_mfma_f32_16x16x32_bf16(af[kcl], b, acc[nt], 0, 0, 0);
            }
        }
        if (rowbase < NN) {
            #pragma unroll
            for (int nt = 0; nt < 8; nt++) {
                int col = half * 128 + nt * 16 + ln;
                float bv = (col < CLS) ? b2[col] : 0.0f;
                #pragma unroll
                for (int j = 0; j < 4; j++) {
                    int r = rowbase + gp * 4 + j;
                    unsigned short hv = f2b(acc[nt][j] + bv);
                    Z[(size_t)r * ZW + col] = hv;
                    if (half == 1 && nt >= 4) B3c[(size_t)r * 64 + (col - 192)] = hv;
                }
            }
        }
    }
}

// ---------------- launch ----------------

extern "C" void kernel_launch(void* const* d_in, const int* in_sizes, int n_in,
                              void* d_out, int out_size, void* d_ws, size_t ws_size,
                              hipStream_t stream) {
    const float* x    = (const float*)d_in[0];
    const int*   esrc = (const int*)d_in[1];
    const int*   edst = (const int*)d_in[2];
    const float* W0   = (const float*)d_in[3];
    const float* b0   = (const float*)d_in[4];
    const float* W1   = (const float*)d_in[5];
    const float* b1   = (const float*)d_in[6];
    const float* W2   = (const float*)d_in[7];
    const float* b2   = (const float*)d_in[8];
    float* out = (float*)d_out;

    char* p = (char*)d_ws;
    auto alloc = [&](size_t bytes) -> void* {
        void* r = (void*)p;
        p += (bytes + 255) & ~(size_t)255;
        return r;
    };
    unsigned short* Abuf = (unsigned short*)alloc((size_t)(NN + 1) * AW * 2);
    unsigned short* Zbuf = (unsigned short*)alloc((size_t)NN * ZW * 2);
    unsigned short* B1b  = (unsigned short*)alloc((size_t)(NN + 1) * 64 * 2);
    unsigned short* B2b  = (unsigned short*)alloc((size_t)(NN + 1) * 64 * 2);
    unsigned short* B3b  = (unsigned short*)alloc((size_t)(NN + 1) * 64 * 2);
    int*   ews     = (int*)alloc((size_t)(NE + NBUK * BSLACK + 64) * 4);   // ~9.6MB
    int*   ebuf    = (int*)alloc((size_t)NE * 4);
    unsigned short* sbuf = (unsigned short*)alloc((size_t)NE * 2);
    int*   hist    = (int*)alloc((size_t)HL2 * 4);
    int*   scanned = (int*)alloc((size_t)(HL2 + 1) * 4);
    int*   bsum    = (int*)alloc(NB_S * 4);
    unsigned short* Wt0 = (unsigned short*)alloc((size_t)128 * AW * 2);
    unsigned short* Wt1 = (unsigned short*)alloc((size_t)128 * AW * 2);
    unsigned short* Wz  = (unsigned short*)alloc((size_t)32768 * 2);
    int*   rp   = (int*)alloc(NN * 4);
    int*   rpe  = (int*)alloc(NN * 4);
    float* dinv = (float*)alloc((NN + 1) * 4);

    const int TB = 256;

    prep_k<<<NB_E + NB_CVT + 2 * NB_WH + NB_WZ, TB, 0, stream>>>(
        (const int4*)esrc, (const int4*)edst, hist,
        x, Abuf, W0, W1, W2, Wt0, Wt1, Wz);
    scanA_k<<<NB_S, TB, 0, stream>>>(hist, bsum);
    scanB_k<<<1, 64, 0, stream>>>(bsum, scanned);
    scanC_k<<<NB_S, TB, 0, stream>>>(hist, bsum, scanned);
    part_k<<<NB_E, TB, 0, stream>>>((const int4*)esrc, (const int4*)edst, scanned, ebuf, sbuf);
    degcnt_k<<<NBUK, TB, 0, stream>>>(scanned, sbuf, dinv);
    bsort_k<<<NBUK, TB, 0, stream>>>(scanned, ebuf, ews, rp, rpe);

    int gSpmm = (NN + 3) / 4;     // 12500
    int gGemm = (NN + 63) / 64;   // 782

    unsigned short* s0 = Abuf + 0 * 128;
    unsigned short* s1 = Abuf + 1 * 128;
    unsigned short* s2 = Abuf + 2 * 128;
    unsigned short* s3 = Abuf + 3 * 128;

    for (int l = 0; l < 2; l++) {
        spmm_k<false><<<gSpmm, TB, 0, stream>>>(s0, nullptr, s1, rp, rpe, ews, dinv);
        spmm_k<true><<<gSpmm, TB, 0, stream>>>(s1, s0, s2, rp, rpe, ews, dinv);
        spmm_k<true><<<gSpmm, TB, 0, stream>>>(s2, s1, s3, rp, rpe, ews, dinv);
        const unsigned short* Wt = (l == 0) ? Wt0 : Wt1;
        const float* bl = (l == 0) ? b0 : b1;
        gemm_hid_k<<<gGemm, TB, 0, stream>>>(Abuf, Wt, bl, Abuf);  // relu'd h -> slice 0
    }

    // last layer: Z = h @ Wcat (+bias on Z0, compact Z3 copy), then Clenshaw
    gemm_z_k<<<gGemm, TB, 0, stream>>>(Abuf, Wz, b2, Zbuf, B3b);
    spmm64_k<0><<<gSpmm, TB, 0, stream>>>(B3b, Zbuf + 128, nullptr,
                                          B2b, nullptr, rp, rpe, ews, dinv);
    spmm64_k<1><<<gSpmm, TB, 0, stream>>>(B2b, Zbuf + 64, Zbuf + 192,
                                          B1b, nullptr, rp, rpe, ews, dinv);
    spmm64_k<2><<<gSpmm, TB, 0, stream>>>(B1b, Zbuf, B2b,
                                          nullptr, out, rp, rpe, ews, dinv);
}